// Round 8
// baseline (240.922 us; speedup 1.0000x reference)
//
#include <hip/hip_runtime.h>

// Problem constants
#define B_ 8
#define V_ 10000
#define E_ 160000
#define DIN 128
#define DOUT 128
#define M_ (B_*V_)          // 80000 rows
#define NINV (1.0f/80000.0f)
#define BN_EPS 1e-5f

// Workspace layout (4-byte units):
#define WS_COUNTS  0            // V_            (zeroed)
#define WS_SUM     10000        // 128           (zeroed)
#define WS_SUMSQ   10128        // 128           (zeroed)
#define WS_ROWPTR  10512        // V_+1
#define WS_CURSOR  20513        // V_
#define WS_SSRC    30513        // E_      -> ends 190513
#define WS_EAS     190520       // E_*8    -> ends 1470520 (32B aligned)
#define WS_S       1470520      // M_      -> ends 1550520
#define WS_WPK     1550520      // 16384 = 32768 f16 (16B aligned)
#define WS_XH      1566904      // 5,120,000 units = 10.24M f16
#define WS_AH      6686904      // 5,120,000 units -> ends 11,806,904 (47.2MB)
#define WS_ZERO_UNITS 10256     // counts + gsum + gsumsq

typedef __attribute__((ext_vector_type(2))) _Float16 half2_t;
typedef __attribute__((ext_vector_type(4))) _Float16 half4_t;
typedef __attribute__((ext_vector_type(8))) _Float16 half8_t;
typedef __attribute__((ext_vector_type(4))) float f32x4;

__device__ inline half2_t i2h(unsigned i) {
    half2_t h; __builtin_memcpy(&h, &i, 4); return h;
}
__device__ inline unsigned h2i(half2_t h) {
    unsigned i; __builtin_memcpy(&i, &h, 4); return i;
}

// ---------------------------------------------------------------------------
// 1) fused prep: X->f16 row-major (blocks 0..9999)
//              + W fragment-major f16 pack (blocks 10000..10015)
//              + dst histogram (blocks 10016..10640)
// ---------------------------------------------------------------------------
__global__ __launch_bounds__(256) void prep_kernel(
    const float* __restrict__ X, _Float16* __restrict__ Xh,
    const float* __restrict__ Wself, const float* __restrict__ Wnode,
    _Float16* __restrict__ Wpk,
    const int* __restrict__ EI, int* __restrict__ counts)
{
    const int blk = blockIdx.x;
    const int t = threadIdx.x;
    if (blk < 10000) {
        int idx = blk * 256 + t;                 // over M_*DIN/4
        float4 v = ((const float4*)X)[idx];
        half4_t o = { (_Float16)v.x, (_Float16)v.y, (_Float16)v.z, (_Float16)v.w };
        ((half4_t*)Xh)[idx] = o;
    } else if (blk < 10016) {
        int g = (blk - 10000) * 256 + t;         // 0..4095
        int pair = g >> 6;                       // (ks,nt)
        int lane = g & 63;
        int ks = pair >> 3;
        int nt = pair & 7;
        int o = nt * 16 + (lane & 15);
        int k = ks * 32 + (lane >> 4) * 8;
        const float* wsrc = (k < 128) ? (Wself + o * 128 + k)
                                      : (Wnode + o * 128 + (k - 128));
        _Float16* dst = Wpk + ((size_t)pair * 64 + lane) * 8;
#pragma unroll
        for (int j = 0; j < 8; ++j) dst[j] = (_Float16)wsrc[j];
    } else {
        int e = (blk - 10016) * 256 + t;
        if (e < E_) atomicAdd(&counts[EI[2 * e + 1]], 1);
    }
}

// ---------------------------------------------------------------------------
// 2) exclusive prefix sum over counts -> row_ptr, cursor (single block)
// ---------------------------------------------------------------------------
__global__ __launch_bounds__(256) void scan_kernel(
    const int* __restrict__ counts, int* __restrict__ row_ptr,
    int* __restrict__ cursor)
{
    __shared__ int psum[256];
    const int t = threadIdx.x;
    const int base = t * 40;              // 256*40 = 10240 >= V_
    int local[40];
    int s = 0;
#pragma unroll
    for (int i = 0; i < 40; ++i) {
        int idx = base + i;
        int c = (idx < V_) ? counts[idx] : 0;
        local[i] = s;
        s += c;
    }
    psum[t] = s;
    __syncthreads();
    for (int off = 1; off < 256; off <<= 1) {
        int v = (t >= off) ? psum[t - off] : 0;
        __syncthreads();
        psum[t] += v;
        __syncthreads();
    }
    int excl = (t == 0) ? 0 : psum[t - 1];
#pragma unroll
    for (int i = 0; i < 40; ++i) {
        int idx = base + i;
        if (idx < V_) {
            int rp = excl + local[i];
            row_ptr[idx] = rp;
            cursor[idx] = rp;
        }
    }
    if (t == 255) row_ptr[V_] = psum[255];
}

// ---------------------------------------------------------------------------
// 3) scatter edges into dst-sorted buckets; also pre-sort edge_attr for all
//    8 batches into bucket order: EAs[p][b]  (kills the scattered EA read)
// ---------------------------------------------------------------------------
__global__ __launch_bounds__(256) void bucket_kernel(
    const int* __restrict__ EI, const float* __restrict__ EA,
    int* __restrict__ cursor, int* __restrict__ ssrc,
    float* __restrict__ EAs)
{
    int e = blockIdx.x * 256 + threadIdx.x;
    if (e < E_) {
        int src = EI[2 * e];
        int dst = EI[2 * e + 1];
        int p = atomicAdd(&cursor[dst], 1);
        ssrc[p] = src;
        float4 v0, v1;
        v0.x = EA[0 * E_ + e]; v0.y = EA[1 * E_ + e];
        v0.z = EA[2 * E_ + e]; v0.w = EA[3 * E_ + e];
        v1.x = EA[4 * E_ + e]; v1.y = EA[5 * E_ + e];
        v1.z = EA[6 * E_ + e]; v1.w = EA[7 * E_ + e];
        *(float4*)(EAs + (size_t)p * 8) = v0;
        *(float4*)(EAs + (size_t)p * 8 + 4) = v1;
    }
}

// ---------------------------------------------------------------------------
// 4) gather-reduce, f16, 2 edges per wave-step, batch-per-XCD swizzled:
//    Ah[b,d,:] = f16( sum_{e:dst=d} Xh[b,src,:] ); S[b,d] = sum ea
// ---------------------------------------------------------------------------
__global__ __launch_bounds__(256) void gather_kernel(
    const _Float16* __restrict__ Xh, const float* __restrict__ EAs,
    const int* __restrict__ row_ptr, const int* __restrict__ ssrc,
    _Float16* __restrict__ Ah, float* __restrict__ S)
{
    const int b = blockIdx.x & 7;             // batch -> XCD
    const int dblk = blockIdx.x >> 3;         // 0..2499
    const int w = threadIdx.x >> 6;           // 4 waves/block
    const int lane = threadIdx.x & 63;
    const int half = lane >> 5;               // which edge of the pair
    const int sl = lane & 31;                 // element group: sl*4 .. sl*4+3
    const int d = dblk * 4 + w;
    const int wid = b * V_ + d;
    const int k0 = row_ptr[d];
    const int k1 = row_ptr[d + 1];
    const _Float16* Xb = Xh + (size_t)b * V_ * DIN + sl * 4;
    half2_t a0 = (half2_t)0, a1 = (half2_t)0;
    float ea = 0.0f;
    for (int kb = k0; kb < k1; kb += 64) {
        int cnt = min(64, k1 - kb);
        int msrc = 0;
        if (lane < cnt) {
            msrc = ssrc[kb + lane];
            ea += EAs[(size_t)(kb + lane) * 8 + b];
        }
        int j = 0;
        for (; j + 8 <= cnt; j += 8) {
#pragma unroll
            for (int u = 0; u < 4; ++u) {
                int s = __shfl(msrc, j + u * 2 + half);
                uint2 v = *(const uint2*)(Xb + (size_t)s * DIN);
                a0 += i2h(v.x);
                a1 += i2h(v.y);
            }
        }
        for (; j + 2 <= cnt; j += 2) {
            int s = __shfl(msrc, j + half);
            uint2 v = *(const uint2*)(Xb + (size_t)s * DIN);
            a0 += i2h(v.x);
            a1 += i2h(v.y);
        }
        if (j < cnt) {
            int s = __shfl(msrc, j);
            if (half == 0) {
                uint2 v = *(const uint2*)(Xb + (size_t)s * DIN);
                a0 += i2h(v.x);
                a1 += i2h(v.y);
            }
        }
    }
    // combine the two edge-parity halves (lane <- lane+32)
    unsigned c0 = __shfl_down(h2i(a0), 32);
    unsigned c1 = __shfl_down(h2i(a1), 32);
    a0 += i2h(c0);
    a1 += i2h(c1);
    // edge_attr wave reduction
    for (int off = 32; off; off >>= 1) ea += __shfl_down(ea, off);
    if (lane == 0) S[wid] = ea;
    if (half == 0) {
        uint2 o;
        o.x = h2i(a0);
        o.y = h2i(a1);
        *(uint2*)(Ah + (size_t)wid * DIN + sl * 4) = o;
    }
}

// ---------------------------------------------------------------------------
// 5) MFMA GEMM (f16) + fused BN stats.
//    64 rows/block -> 1250 blocks (2x the wave parallelism of R6's 625);
//    wave = 16 rows x 128 cols (8 n-tiles), one m-tile -> low VGPR.
// ---------------------------------------------------------------------------
__global__ __launch_bounds__(256) void mfma_gemm_kernel(
    const _Float16* __restrict__ Xh, const _Float16* __restrict__ Ah,
    const _Float16* __restrict__ Wpk, const float* __restrict__ S,
    const float* __restrict__ bself, const float* __restrict__ wedge,
    float* __restrict__ H, float* __restrict__ gsum, float* __restrict__ gsumsq)
{
    __shared__ float cs[128];
    __shared__ float css[128];
    const int t = threadIdx.x;
    const int wave = t >> 6;
    const int lane = t & 63;
    const int quad = lane >> 4;
    const int ln = lane & 15;
    const int rowbase = blockIdx.x * 64 + wave * 16;
    const int m = rowbase + ln;           // A-frag row

    if (t < 128) { cs[t] = 0.0f; css[t] = 0.0f; }

    f32x4 acc[8];
#pragma unroll
    for (int nt = 0; nt < 8; ++nt) acc[nt] = (f32x4){0.f, 0.f, 0.f, 0.f};

    const _Float16* Xp = Xh + (size_t)m * DIN + quad * 8;
    const _Float16* Ap = Ah + (size_t)m * DIN + quad * 8;
    const _Float16* Wl = Wpk + lane * 8;

#pragma unroll
    for (int ks = 0; ks < 8; ++ks) {
        half8_t af = (ks < 4) ? *(const half8_t*)(Xp + ks * 32)
                              : *(const half8_t*)(Ap + (ks - 4) * 32);
#pragma unroll
        for (int nt = 0; nt < 8; ++nt) {
            half8_t bfr = *(const half8_t*)(Wl + (size_t)(ks * 8 + nt) * 512);
            acc[nt] = __builtin_amdgcn_mfma_f32_16x16x32_f16(af, bfr, acc[nt], 0, 0, 0);
        }
    }

    // epilogue: bias + S*w_edge, store H, accumulate stats
    const int rbase = rowbase + quad * 4;    // C/D: col=ln, row=quad*4+r
    float sv[4];
#pragma unroll
    for (int r = 0; r < 4; ++r) sv[r] = S[rbase + r];
    float bs[8], we[8];
#pragma unroll
    for (int nt = 0; nt < 8; ++nt) {
        int c = nt * 16 + ln;
        bs[nt] = bself[c];
        we[nt] = wedge[c];
    }
    float psum[8], psq[8];
#pragma unroll
    for (int nt = 0; nt < 8; ++nt) { psum[nt] = 0.0f; psq[nt] = 0.0f; }
#pragma unroll
    for (int r = 0; r < 4; ++r) {
        float* Hr = H + (size_t)(rbase + r) * DOUT + ln;
#pragma unroll
        for (int nt = 0; nt < 8; ++nt) {
            float h = acc[nt][r] + bs[nt] + sv[r] * we[nt];
            Hr[nt * 16] = h;
            psum[nt] += h;
            psq[nt] += h * h;
        }
    }
    // reduce across quads (lanes ln, ln+16, ln+32, ln+48)
#pragma unroll
    for (int nt = 0; nt < 8; ++nt) {
        psum[nt] += __shfl_down(psum[nt], 32);
        psum[nt] += __shfl_down(psum[nt], 16);
        psq[nt] += __shfl_down(psq[nt], 32);
        psq[nt] += __shfl_down(psq[nt], 16);
    }
    __syncthreads();   // cs/css zeros visible
    if (lane < 16) {
#pragma unroll
        for (int nt = 0; nt < 8; ++nt) {
            atomicAdd(&cs[nt * 16 + ln], psum[nt]);
            atomicAdd(&css[nt * 16 + ln], psq[nt]);
        }
    }
    __syncthreads();
    if (t < 128) {
        atomicAdd(&gsum[t], cs[t]);
        atomicAdd(&gsumsq[t], css[t]);
    }
}

// ---------------------------------------------------------------------------
// 6) normalize + ReLU in place (finalize fused)
// ---------------------------------------------------------------------------
__global__ __launch_bounds__(256) void norm_relu_kernel(
    float* __restrict__ H, const float* __restrict__ gsum,
    const float* __restrict__ gsumsq, const float* __restrict__ gamma,
    const float* __restrict__ beta)
{
    int idx = blockIdx.x * 256 + threadIdx.x;   // over M_*128/4 float4s
    int o4 = (idx & 31) * 4;
    float4 s = *(const float4*)(gsum + o4);
    float4 q = *(const float4*)(gsumsq + o4);
    float4 g = *(const float4*)(gamma + o4);
    float4 bt = *(const float4*)(beta + o4);
    float4 sc, sh;
    {
        float m0 = s.x * NINV, m1 = s.y * NINV, m2 = s.z * NINV, m3 = s.w * NINV;
        float r0 = rsqrtf(q.x * NINV - m0 * m0 + BN_EPS);
        float r1 = rsqrtf(q.y * NINV - m1 * m1 + BN_EPS);
        float r2 = rsqrtf(q.z * NINV - m2 * m2 + BN_EPS);
        float r3 = rsqrtf(q.w * NINV - m3 * m3 + BN_EPS);
        sc.x = g.x * r0; sc.y = g.y * r1; sc.z = g.z * r2; sc.w = g.w * r3;
        sh.x = bt.x - m0 * sc.x; sh.y = bt.y - m1 * sc.y;
        sh.z = bt.z - m2 * sc.z; sh.w = bt.w - m3 * sc.w;
    }
    float4 h = ((const float4*)H)[idx];
    h.x = fmaxf(h.x * sc.x + sh.x, 0.0f);
    h.y = fmaxf(h.y * sc.y + sh.y, 0.0f);
    h.z = fmaxf(h.z * sc.z + sh.z, 0.0f);
    h.w = fmaxf(h.w * sc.w + sh.w, 0.0f);
    ((float4*)H)[idx] = h;
}

// ---------------------------------------------------------------------------
extern "C" void kernel_launch(void* const* d_in, const int* in_sizes, int n_in,
                              void* d_out, int out_size, void* d_ws, size_t ws_size,
                              hipStream_t stream)
{
    const float* X      = (const float*)d_in[0];
    const float* EA     = (const float*)d_in[1];
    const float* Wnode  = (const float*)d_in[2];
    const float* Wedge  = (const float*)d_in[3];
    const float* Wself  = (const float*)d_in[4];
    const float* bself  = (const float*)d_in[5];
    const float* gamma  = (const float*)d_in[6];
    const float* beta   = (const float*)d_in[7];
    const int*   EI     = (const int*)d_in[8];

    int*   wsI    = (int*)d_ws;
    float* wsF    = (float*)d_ws;
    int*   counts = wsI + WS_COUNTS;
    float* gsum   = wsF + WS_SUM;
    float* gsumsq = wsF + WS_SUMSQ;
    int*   rowptr = wsI + WS_ROWPTR;
    int*   cursor = wsI + WS_CURSOR;
    int*   ssrc   = wsI + WS_SSRC;
    float* EAs    = wsF + WS_EAS;
    float* S      = wsF + WS_S;
    _Float16* Wpk = (_Float16*)(wsI + WS_WPK);
    _Float16* Xh  = (_Float16*)(wsI + WS_XH);
    _Float16* Ah  = (_Float16*)(wsI + WS_AH);
    float* H      = (float*)d_out;

    hipMemsetAsync(d_ws, 0, (size_t)WS_ZERO_UNITS * 4, stream);

    // fused prep: xcvt (10000 blocks) + W pack (16) + hist (625)
    prep_kernel<<<10641, 256, 0, stream>>>(X, Xh, Wself, Wnode, Wpk, EI, counts);
    scan_kernel<<<1, 256, 0, stream>>>(counts, rowptr, cursor);
    bucket_kernel<<<(E_ + 255) / 256, 256, 0, stream>>>(EI, EA, cursor, ssrc, EAs);

    // gather-reduce -> Ah, S  (batch-per-XCD swizzle, 2 edges/wave-step)
    gather_kernel<<<M_ / 4, 256, 0, stream>>>(Xh, EAs, rowptr, ssrc, Ah, S);

    // MFMA GEMM + stats -> H, gsum, gsumsq (64 rows/block, 1250 blocks)
    mfma_gemm_kernel<<<M_ / 64, 256, 0, stream>>>(Xh, Ah, Wpk, S, bself, Wedge,
                                                  H, gsum, gsumsq);

    // normalize + relu (finalize fused)
    norm_relu_kernel<<<(M_ * DOUT / 4) / 256, 256, 0, stream>>>(H, gsum, gsumsq,
                                                                gamma, beta);
}